// Round 2
// baseline (288.092 us; speedup 1.0000x reference)
//
#include <hip/hip_runtime.h>
#include <math.h>

#define BLOCK 256
// Layer cell counts (b=32, 3 anchors):
//  L0: 32*3*13*13 = 16224  -> 64 blocks   (13x13, anchors 6,7,8)
//  L1: 32*3*26*26 = 64896  -> 254 blocks  (26x26, anchors 3,4,5)
//  L2: 32*3*52*52 = 259584 -> 1014 blocks (52x52, anchors 0,1,2)
#define NB0 64
#define NB1 254
#define NB2 1014
#define NBLOCKS (NB0 + NB1 + NB2)

// 4-byte-aligned float4 (used only for broadcast-ish target loads; L2-resident)
typedef float f4a __attribute__((ext_vector_type(4), aligned(4)));

// anchors ordered [layer][a]: layer0 = ANCHORS[6,7,8], layer1 = [3,4,5], layer2 = [0,1,2]
__constant__ float c_anch[9][2] = {
    {116.f, 90.f}, {156.f, 198.f}, {373.f, 326.f},
    { 30.f, 61.f}, { 62.f,  45.f}, { 59.f, 119.f},
    { 10.f, 13.f}, { 16.f,  30.f}, { 33.f,  23.f}
};

// stable softplus: log(1+exp(x)) = max(x,0) + log(1+exp(-|x|))
__device__ __forceinline__ float softplusf(float x) {
    float ax = fabsf(x);
    return fmaxf(x, 0.f) + __logf(1.f + __expf(-ax));
}

__device__ __forceinline__ float sigmoidf(float x) {
    return __fdividef(1.f, 1.f + __expf(-x));
}

// __launch_bounds__(256, 8): 8 waves/EU -> caps VGPR at 64 so occupancy stays
// grid-limited (round-1 showed VGPR 80 -> 6 waves/EU -> regression).
__global__ __launch_bounds__(BLOCK, 8) void yolo_loss_main(
    const float* __restrict__ p0, const float* __restrict__ p1, const float* __restrict__ p2,
    const float* __restrict__ t0, const float* __restrict__ t1, const float* __restrict__ t2,
    const float* __restrict__ tgt, float* __restrict__ partials)
{
    // Staging buffer for y_true channels. Stride 17 (odd) -> stride-17 reads
    // sh[tid][c] hit all 32 banks (2 lanes/bank = free); writes are 16-wide
    // contiguous runs at offsets 17*cell (2-way max = free).
    __shared__ float sh[BLOCK][17];   // 17.4 KB

    int blk = blockIdx.x;
    const float* pred;
    const float* tru;
    int layer, g, cells, bbase;
    if (blk < NB0)            { layer = 0; pred = p0; tru = t0; g = 13; cells = 16224;  bbase = 0; }
    else if (blk < NB0 + NB1) { layer = 1; pred = p1; tru = t1; g = 26; cells = 64896;  bbase = NB0; }
    else                      { layer = 2; pred = p2; tru = t2; g = 52; cells = 259584; bbase = NB0 + NB1; }

    int tid = threadIdx.x;
    int cell0 = (blk - bbase) * BLOCK;
    int idx = cell0 + tid;
    bool active = idx < cells;
    int nvalid = min(BLOCK, cells - cell0);     // >= 96 for all blocks
    const float* trow = tru + (size_t)cell0 * 85;

    // ---- stage y_true head channels [0..5) for all cells in block ----
    // flat f = cell*5 + ch: 64 consecutive lanes span ~13 cells x 20B contiguous
    // -> ~13 lines/instr instead of 64 (the round-0 gather pattern).
#pragma unroll
    for (int k = 0; k < 5; k++) {
        int f = k * BLOCK + tid;            // 0..1279
        int cell = f / 5;
        int ch = f - cell * 5;
        int cc = min(cell, nvalid - 1);     // clamp: duplicate a valid cell, consume is guarded
        sh[cell][ch] = trow[(size_t)cc * 85 + ch];
    }
    __syncthreads();

    int cidx = active ? idx : (cells - 1);
    int hw = g * g;
    int ij = cidx % hw;
    int a  = (cidx / hw) % 3;
    int b  = cidx / (3 * hw);
    int i  = ij / g;
    int j  = ij - i * g;
    // raw[b][a][i][j][c] = y_pred[b][a*85+c][i][j]  (channel stride = hw, lane-coalesced)
    const float* pb = pred + (size_t)((b * 3 + a) * 85) * hw + ij;

    float acc = 0.f;
    float mask = 0.f;

    if (active) {
        float y0 = sh[tid][0], y1 = sh[tid][1], y2 = sh[tid][2], y3 = sh[tid][3];
        mask = sh[tid][4];

        float r0 = pb[0];
        float r1 = pb[hw];
        float r2 = pb[2 * hw];
        float r3 = pb[3 * hw];
        float r4 = pb[4 * hw];

        float gf = (float)g, gx = (float)j, gy = (float)i;
        float aw = c_anch[layer * 3 + a][0];
        float ah = c_anch[layer * 3 + a][1];

        // ---- xy loss: bce(sigmoid(r), t) = softplus(r) - t*r ----
        float true_x = y0 * gf - gx;
        float true_y = y1 * gf - gy;
        float ls = 2.f - y2 * y3;   // loss_scale
        float lxy = (softplusf(r0) - true_x * r0) + (softplusf(r1) - true_y * r1);
        acc += mask * ls * lxy;

        // ---- wh loss ----
        float tw = __logf(y2 * (416.f / aw));
        float th = __logf(y3 * (416.f / ah));
        float dw = r2 - tw, dh = r3 - th;
        acc += mask * ls * 0.5f * (dw * dw + dh * dh);

        // ---- conf bce ----
        float cbce = softplusf(r4) - mask * r4;

        // ---- IoU vs 20 targets -> neg mask ----
        float sx = sigmoidf(r0);
        float sy = sigmoidf(r1);
        float bx = __fdividef(sx + gx, gf);
        float by = __fdividef(sy + gy, gf);
        float bw = __expf(r2) * aw * (1.f / 416.f);
        float bh = __expf(r3) * ah * (1.f / 416.f);
        float a1 = bw * bh;
        float b1minx = bx - 0.5f * bw, b1maxx = bx + 0.5f * bw;
        float b1miny = by - 0.5f * bh, b1maxy = by + 0.5f * bh;

        const float* tg = tgt + b * 20 * 5;
        float best = 0.f;
#pragma unroll 5
        for (int k = 0; k < 20; k++) {
            f4a t = *reinterpret_cast<const f4a*>(tg + k * 5);  // tx,ty,tw,th
            float hw2 = 0.5f * t.z, hh2 = 0.5f * t.w;
            float iw = fminf(b1maxx, t.x + hw2) - fmaxf(b1minx, t.x - hw2);
            float ih = fminf(b1maxy, t.y + hh2) - fmaxf(b1miny, t.y - hh2);
            iw = fmaxf(iw, 0.f);
            ih = fmaxf(ih, 0.f);
            float inter = iw * ih;
            float iou = __fdividef(inter, a1 + t.z * t.w - inter);
            best = fmaxf(best, iou);
        }
        float neg = (best < 0.5f) ? 1.f : 0.f;
        acc += mask * cbce + (1.f - mask) * neg * cbce;
    }

    // ---- class loss: 80 channels in 5 chunks of 16, y_true staged via LDS ----
    // Stage mapping f = cell*16 + ch: a wave's 64 lanes cover 4 cells x 64B
    // contiguous -> ~6 lines/instr vs 64 for the direct gather (10x+ fewer
    // TA line-requests on the dominant stream).
    float cls = 0.f;
    for (int q = 0; q < 5; q++) {
        __syncthreads();        // previous chunk (or head) fully consumed
#pragma unroll
        for (int k = 0; k < 16; k++) {
            int f = k * BLOCK + tid;        // 0..4095
            int cell = f >> 4;
            int ch = f & 15;
            int cc = min(cell, nvalid - 1);
            sh[cell][ch] = trow[(size_t)cc * 85 + 5 + q * 16 + ch];
        }
        __syncthreads();
        if (active) {
#pragma unroll
            for (int c = 0; c < 16; c++) {
                float x = pb[(size_t)(5 + q * 16 + c) * hw];
                float t = sh[tid][c];
                cls += softplusf(x) - t * x;
            }
        }
    }
    if (active) acc += mask * cls;

    // ---- block reduction: wave shuffle then LDS ----
    for (int off = 32; off > 0; off >>= 1)
        acc += __shfl_down(acc, off, 64);
    __shared__ float shr[BLOCK / 64];
    if ((threadIdx.x & 63) == 0)
        shr[threadIdx.x >> 6] = acc;
    __syncthreads();
    if (threadIdx.x == 0) {
        float s = 0.f;
        for (int wv = 0; wv < BLOCK / 64; wv++) s += shr[wv];
        partials[blockIdx.x] = s;
    }
}

__global__ __launch_bounds__(BLOCK) void yolo_loss_reduce(
    const float* __restrict__ partials, float* __restrict__ out)
{
    float s = 0.f;
    for (int i = threadIdx.x; i < NBLOCKS; i += BLOCK)
        s += partials[i];
    for (int off = 32; off > 0; off >>= 1)
        s += __shfl_down(s, off, 64);
    __shared__ float sh[BLOCK / 64];
    if ((threadIdx.x & 63) == 0)
        sh[threadIdx.x >> 6] = s;
    __syncthreads();
    if (threadIdx.x == 0) {
        float tot = 0.f;
        for (int wv = 0; wv < BLOCK / 64; wv++) tot += sh[wv];
        out[0] = tot;
    }
}

extern "C" void kernel_launch(void* const* d_in, const int* in_sizes, int n_in,
                              void* d_out, int out_size, void* d_ws, size_t ws_size,
                              hipStream_t stream) {
    // setup_inputs() dict order is INTERLEAVED:
    //   d_in[0]=y_pred0, d_in[1]=y_true0, d_in[2]=y_pred1, d_in[3]=y_true1,
    //   d_in[4]=y_pred2, d_in[5]=y_true2, d_in[6]=target
    const float* p0  = (const float*)d_in[0];
    const float* t0  = (const float*)d_in[1];
    const float* p1  = (const float*)d_in[2];
    const float* t1  = (const float*)d_in[3];
    const float* p2  = (const float*)d_in[4];
    const float* t2  = (const float*)d_in[5];
    const float* tgt = (const float*)d_in[6];
    float* partials  = (float*)d_ws;   // NBLOCKS floats; every slot written each call

    yolo_loss_main<<<NBLOCKS, BLOCK, 0, stream>>>(p0, p1, p2, t0, t1, t2, tgt, partials);
    yolo_loss_reduce<<<1, BLOCK, 0, stream>>>(partials, (float*)d_out);
}

// Round 3
// 275.468 us; speedup vs baseline: 1.0458x; 1.0458x over previous
//
#include <hip/hip_runtime.h>
#include <math.h>

#define BLOCK 256
// Layer cell counts (b=32, 3 anchors):
//  L0: 32*3*13*13 = 16224  -> 64 blocks   (13x13, anchors 6,7,8)
//  L1: 32*3*26*26 = 64896  -> 254 blocks  (26x26, anchors 3,4,5)
//  L2: 32*3*52*52 = 259584 -> 1014 blocks (52x52, anchors 0,1,2)
#define NB0 64
#define NB1 254
#define NB2 1014
#define NBLOCKS (NB0 + NB1 + NB2)

// 4-byte-aligned float4 (only for target loads: 20B stride, L2-resident broadcast)
typedef float f4a __attribute__((ext_vector_type(4), aligned(4)));

// anchors ordered [layer][a]: layer0 = ANCHORS[6,7,8], layer1 = [3,4,5], layer2 = [0,1,2]
__constant__ float c_anch[9][2] = {
    {116.f, 90.f}, {156.f, 198.f}, {373.f, 326.f},
    { 30.f, 61.f}, { 62.f,  45.f}, { 59.f, 119.f},
    { 10.f, 13.f}, { 16.f,  30.f}, { 33.f,  23.f}
};

// stable softplus: log(1+exp(x)) = max(x,0) + log(1+exp(-|x|))
__device__ __forceinline__ float softplusf(float x) {
    float ax = fabsf(x);
    return fmaxf(x, 0.f) + __logf(1.f + __expf(-ax));
}

__device__ __forceinline__ float sigmoidf(float x) {
    return __fdividef(1.f, 1.f + __expf(-x));
}

// ---- pipelined y_true staging helpers ----
// Chunk Q covers y_true channels [16Q, min(16Q+16,85)) for all 256 cells of the
// block. Flat mapping f = k*BLOCK+tid -> (cell, ch): one wave's 64 lanes cover
// 4 cells x 64B contiguous (~6-8 lines/instr vs 64 for the direct gather).
// All indices compile-time (template Q, full unroll) so reg[] stays in VGPRs.

template<int Q>
__device__ __forceinline__ void stage_issue(const float* __restrict__ trow,
                                            int tid, int nvalid, float* reg) {
    constexpr int nch = (Q == 5) ? 5 : 16;
#pragma unroll
    for (int k = 0; k < nch; k++) {
        int f = k * BLOCK + tid;
        int cell = (Q == 5) ? (f / 5) : (f >> 4);
        int ch = f - cell * nch;
        int cc = min(cell, nvalid - 1);   // clamp: duplicate a valid row; consume is guarded
        reg[k] = trow[(size_t)cc * 85 + Q * 16 + ch];
    }
}

template<int Q>
__device__ __forceinline__ void stage_write(float (&sh)[BLOCK][17], int tid,
                                            const float* reg) {
    constexpr int nch = (Q == 5) ? 5 : 16;
#pragma unroll
    for (int k = 0; k < nch; k++) {
        int f = k * BLOCK + tid;
        int cell = (Q == 5) ? (f / 5) : (f >> 4);
        int ch = f - cell * nch;
        sh[cell][ch] = reg[k];
    }
}

template<int Q>
__device__ __forceinline__ float consume_cls(const float (&sh)[BLOCK][17],
                                             const float* __restrict__ pb,
                                             int tid, int hw) {
    constexpr int nch = (Q == 5) ? 5 : 16;
    float cls = 0.f;
#pragma unroll
    for (int c = 0; c < nch; c++) {
        float x = pb[(size_t)(Q * 16 + c) * hw];
        float t = sh[tid][c];
        cls += softplusf(x) - t * x;
    }
    return cls;
}

// __launch_bounds__(256,4): 4 blocks/CU (LDS-limited anyway at 34.8KB) -> VGPR
// budget 128 for the 32 in-flight staged values + 16 pred loads per chunk.
__global__ __launch_bounds__(BLOCK, 4) void yolo_loss_main(
    const float* __restrict__ p0, const float* __restrict__ p1, const float* __restrict__ p2,
    const float* __restrict__ t0, const float* __restrict__ t1, const float* __restrict__ t2,
    const float* __restrict__ tgt, float* __restrict__ partials)
{
    // Double-buffered staging: one barrier per chunk. Stride 17 -> consume
    // reads sh[tid][c] at lane-stride 17 floats (odd -> all 32 banks, free);
    // writes are 16-wide runs (<=3-way overlap on 16 instrs, negligible).
    __shared__ float shA[BLOCK][17];
    __shared__ float shB[BLOCK][17];

    int blk = blockIdx.x;
    const float* pred;
    const float* tru;
    int layer, g, cells, bbase;
    if (blk < NB0)            { layer = 0; pred = p0; tru = t0; g = 13; cells = 16224;  bbase = 0; }
    else if (blk < NB0 + NB1) { layer = 1; pred = p1; tru = t1; g = 26; cells = 64896;  bbase = NB0; }
    else                      { layer = 2; pred = p2; tru = t2; g = 52; cells = 259584; bbase = NB0 + NB1; }

    int tid = threadIdx.x;
    int cell0 = (blk - bbase) * BLOCK;
    int idx = cell0 + tid;
    bool active = idx < cells;
    int nvalid = min(BLOCK, cells - cell0);     // >= 96 for all blocks
    const float* trow = tru + (size_t)cell0 * 85;

    int cidx = active ? idx : (cells - 1);
    int hw = g * g;
    int ij = cidx % hw;
    int a  = (cidx / hw) % 3;
    int b  = cidx / (3 * hw);
    int i  = ij / g;
    int j  = ij - i * g;
    // raw[b][a][i][j][c] = y_pred[b][a*85+c][i][j]  (channel stride = hw, lane-coalesced)
    const float* pb = pred + (size_t)((b * 3 + a) * 85) * hw + ij;

    float rA[16], rB[16];

    // ---- pipeline prologue: chunks 0,1 in flight ----
    stage_issue<0>(trow, tid, nvalid, rA);
    stage_issue<1>(trow, tid, nvalid, rB);
    stage_write<0>(shA, tid, rA);
    __syncthreads();                            // chunk 0 visible

    float acc = 0.f, cls = 0.f, mask = 0.f;

    // ---- P1: consume chunk 0 (head + classes 5..15) ----
    stage_issue<2>(trow, tid, nvalid, rA);      // 2 chunks ahead, hides HBM latency
    if (active) {
        float y0 = shA[tid][0], y1 = shA[tid][1], y2 = shA[tid][2], y3 = shA[tid][3];
        mask = shA[tid][4];

        float r0 = pb[0];
        float r1 = pb[hw];
        float r2 = pb[2 * hw];
        float r3 = pb[3 * hw];
        float r4 = pb[4 * hw];

        float gf = (float)g, gx = (float)j, gy = (float)i;
        float aw = c_anch[layer * 3 + a][0];
        float ah = c_anch[layer * 3 + a][1];

        // xy loss: bce(sigmoid(r), t) = softplus(r) - t*r
        float true_x = y0 * gf - gx;
        float true_y = y1 * gf - gy;
        float ls = 2.f - y2 * y3;   // loss_scale
        float lxy = (softplusf(r0) - true_x * r0) + (softplusf(r1) - true_y * r1);
        acc += mask * ls * lxy;

        // wh loss
        float tw = __logf(y2 * (416.f / aw));
        float th = __logf(y3 * (416.f / ah));
        float dw = r2 - tw, dh = r3 - th;
        acc += mask * ls * 0.5f * (dw * dw + dh * dh);

        // conf bce
        float cbce = softplusf(r4) - mask * r4;

        // IoU vs 20 targets -> neg mask
        float sx = sigmoidf(r0);
        float sy = sigmoidf(r1);
        float bx = __fdividef(sx + gx, gf);
        float by = __fdividef(sy + gy, gf);
        float bw = __expf(r2) * aw * (1.f / 416.f);
        float bh = __expf(r3) * ah * (1.f / 416.f);
        float a1 = bw * bh;
        float b1minx = bx - 0.5f * bw, b1maxx = bx + 0.5f * bw;
        float b1miny = by - 0.5f * bh, b1maxy = by + 0.5f * bh;

        const float* tg = tgt + b * 20 * 5;
        float best = 0.f;
#pragma unroll 5
        for (int k = 0; k < 20; k++) {
            f4a t = *reinterpret_cast<const f4a*>(tg + k * 5);  // tx,ty,tw,th
            float hw2 = 0.5f * t.z, hh2 = 0.5f * t.w;
            float iw = fminf(b1maxx, t.x + hw2) - fmaxf(b1minx, t.x - hw2);
            float ih = fminf(b1maxy, t.y + hh2) - fmaxf(b1miny, t.y - hh2);
            iw = fmaxf(iw, 0.f);
            ih = fmaxf(ih, 0.f);
            float inter = iw * ih;
            float iou = __fdividef(inter, a1 + t.z * t.w - inter);
            best = fmaxf(best, iou);
        }
        float neg = (best < 0.5f) ? 1.f : 0.f;
        acc += mask * cbce + (1.f - mask) * neg * cbce;

        // classes in chunk 0 (raw channels 5..15)
#pragma unroll
        for (int c = 5; c < 16; c++) {
            float x = pb[(size_t)c * hw];
            float t = shA[tid][c];
            cls += softplusf(x) - t * x;
        }
    }
    stage_write<1>(shB, tid, rB);               // rB free after this
    __syncthreads();                            // chunk 1 visible

    // ---- P2: chunk 1 ----
    stage_issue<3>(trow, tid, nvalid, rB);
    if (active) cls += consume_cls<1>(shB, pb, tid, hw);
    stage_write<2>(shA, tid, rA);               // shA reuse: consume(0) done before last sync
    __syncthreads();

    // ---- P3: chunk 2 ----
    stage_issue<4>(trow, tid, nvalid, rA);
    if (active) cls += consume_cls<2>(shA, pb, tid, hw);
    stage_write<3>(shB, tid, rB);
    __syncthreads();

    // ---- P4: chunk 3 ----
    stage_issue<5>(trow, tid, nvalid, rB);
    if (active) cls += consume_cls<3>(shB, pb, tid, hw);
    stage_write<4>(shA, tid, rA);
    __syncthreads();

    // ---- P5: chunk 4 ----
    if (active) cls += consume_cls<4>(shA, pb, tid, hw);
    stage_write<5>(shB, tid, rB);
    __syncthreads();

    // ---- P6: chunk 5 (channels 80..84) ----
    if (active) {
        cls += consume_cls<5>(shB, pb, tid, hw);
        acc += mask * cls;
    }

    // ---- block reduction: wave shuffle then LDS ----
    for (int off = 32; off > 0; off >>= 1)
        acc += __shfl_down(acc, off, 64);
    __shared__ float shr[BLOCK / 64];
    if ((threadIdx.x & 63) == 0)
        shr[threadIdx.x >> 6] = acc;
    __syncthreads();
    if (threadIdx.x == 0) {
        float s = 0.f;
        for (int wv = 0; wv < BLOCK / 64; wv++) s += shr[wv];
        partials[blockIdx.x] = s;
    }
}

__global__ __launch_bounds__(BLOCK) void yolo_loss_reduce(
    const float* __restrict__ partials, float* __restrict__ out)
{
    float s = 0.f;
    for (int i = threadIdx.x; i < NBLOCKS; i += BLOCK)
        s += partials[i];
    for (int off = 32; off > 0; off >>= 1)
        s += __shfl_down(s, off, 64);
    __shared__ float sh[BLOCK / 64];
    if ((threadIdx.x & 63) == 0)
        sh[threadIdx.x >> 6] = s;
    __syncthreads();
    if (threadIdx.x == 0) {
        float tot = 0.f;
        for (int wv = 0; wv < BLOCK / 64; wv++) tot += sh[wv];
        out[0] = tot;
    }
}

extern "C" void kernel_launch(void* const* d_in, const int* in_sizes, int n_in,
                              void* d_out, int out_size, void* d_ws, size_t ws_size,
                              hipStream_t stream) {
    // setup_inputs() dict order is INTERLEAVED:
    //   d_in[0]=y_pred0, d_in[1]=y_true0, d_in[2]=y_pred1, d_in[3]=y_true1,
    //   d_in[4]=y_pred2, d_in[5]=y_true2, d_in[6]=target
    const float* p0  = (const float*)d_in[0];
    const float* t0  = (const float*)d_in[1];
    const float* p1  = (const float*)d_in[2];
    const float* t1  = (const float*)d_in[3];
    const float* p2  = (const float*)d_in[4];
    const float* t2  = (const float*)d_in[5];
    const float* tgt = (const float*)d_in[6];
    float* partials  = (float*)d_ws;   // NBLOCKS floats; every slot written each call

    yolo_loss_main<<<NBLOCKS, BLOCK, 0, stream>>>(p0, p1, p2, t0, t1, t2, tgt, partials);
    yolo_loss_reduce<<<1, BLOCK, 0, stream>>>(partials, (float*)d_out);
}

// Round 4
// 253.054 us; speedup vs baseline: 1.1385x; 1.0886x over previous
//
#include <hip/hip_runtime.h>
#include <math.h>

#define BLOCK 256
// Layer cell counts (b=32, 3 anchors):
//  L0: 32*3*13*13 = 16224  -> 64 blocks   (13x13, anchors 6,7,8)
//  L1: 32*3*26*26 = 64896  -> 254 blocks  (26x26, anchors 3,4,5)
//  L2: 32*3*52*52 = 259584 -> 1014 blocks (52x52, anchors 0,1,2)
#define NB0 64
#define NB1 254
#define NB2 1014
#define NBLOCKS (NB0 + NB1 + NB2)

// 4-byte-aligned float4 (only for target loads: 20B stride, L1/L2-resident broadcast)
typedef float f4a __attribute__((ext_vector_type(4), aligned(4)));

// anchors ordered [layer][a]: layer0 = ANCHORS[6,7,8], layer1 = [3,4,5], layer2 = [0,1,2]
__constant__ float c_anch[9][2] = {
    {116.f, 90.f}, {156.f, 198.f}, {373.f, 326.f},
    { 30.f, 61.f}, { 62.f,  45.f}, { 59.f, 119.f},
    { 10.f, 13.f}, { 16.f,  30.f}, { 33.f,  23.f}
};

// stable softplus: log(1+exp(x)) = max(x,0) + log(1+exp(-|x|))
__device__ __forceinline__ float softplusf(float x) {
    float ax = fabsf(x);
    return fmaxf(x, 0.f) + __logf(1.f + __expf(-ax));
}

__device__ __forceinline__ float sigmoidf(float x) {
    return __fdividef(1.f, 1.f + __expf(-x));
}

// ---- wave-private y_true staging (NO __syncthreads: a wave's ds_writes are
// visible to itself via the in-order DS pipe + lgkmcnt waits the compiler
// inserts automatically for same-array dependences). ----
//
// Class chunk Q = channels [5+16Q, 5+16Q+16) for this wave's 64 cells.
// Stage mapping: instr k, lane l -> cell = k*4 + (l>>4), ch = l&15.
// 64 lanes cover 4 runs of 64B (stride 340B) ~6-8 lines/instr vs 64 for the
// direct gather (R0's saturated-L1 failure mode). Fast path is pure
// base + lane_offset + compile-time-constant addressing.

template<int Q>
__device__ __forceinline__ void stage_cls(const float* __restrict__ tw, int lane,
                                          int nvc, bool full, float* r) {
    if (full) {
        int lo = (lane >> 4) * 85 + (lane & 15);
#pragma unroll
        for (int k = 0; k < 16; k++)
            r[k] = tw[lo + k * 340 + 5 + Q * 16];
    } else {
        // exactly one wave in the whole grid takes this path (L0 blk63 wv1)
#pragma unroll
        for (int k = 0; k < 16; k++) {
            int cc = min(k * 4 + (lane >> 4), nvc - 1);
            r[k] = tw[cc * 85 + (lane & 15) + 5 + Q * 16];
        }
    }
}

__device__ __forceinline__ void write_cls(float (*S)[17], int lane, const float* r) {
#pragma unroll
    for (int k = 0; k < 16; k++)
        S[k * 4 + (lane >> 4)][lane & 15] = r[k];
}

template<int Q>
__device__ __forceinline__ float consume_cls(const float (*S)[17],
                                             const float* __restrict__ pb,
                                             int lane, int hw) {
    float cls = 0.f;
#pragma unroll
    for (int c = 0; c < 16; c++) {
        float x = pb[(size_t)((5 + Q * 16 + c) * hw)];   // lane-coalesced
        float t = S[lane][c];                             // stride-17: 2-way = free
        cls += softplusf(x) - t * x;
    }
    return cls;
}

// __launch_bounds__(256,6): grid needs ~5.2 blocks/CU resident (whole grid
// fits on chip) -> 6 waves/SIMD target caps VGPR at 84. LDS 17.4KB allows 6+.
__global__ __launch_bounds__(BLOCK, 6) void yolo_loss_main(
    const float* __restrict__ p0, const float* __restrict__ p1, const float* __restrict__ p2,
    const float* __restrict__ t0, const float* __restrict__ t1, const float* __restrict__ t2,
    const float* __restrict__ tgt, float* __restrict__ partials)
{
    // per-wave private tiles -> no cross-wave coordination, no barriers
    __shared__ float sh[4][64][17];   // 17408 B

    int blk = blockIdx.x;
    const float* pred;
    const float* tru;
    int layer, g, cells, bbase;
    if (blk < NB0)            { layer = 0; pred = p0; tru = t0; g = 13; cells = 16224;  bbase = 0; }
    else if (blk < NB0 + NB1) { layer = 1; pred = p1; tru = t1; g = 26; cells = 64896;  bbase = NB0; }
    else                      { layer = 2; pred = p2; tru = t2; g = 52; cells = 259584; bbase = NB0 + NB1; }

    int tid = threadIdx.x;
    int lane = tid & 63;
    int wv = tid >> 6;
    int cell0 = (blk - bbase) * BLOCK + wv * 64;   // this wave's first cell
    int nv = cells - cell0;                        // valid cells for this wave
    float acc = 0.f;

    if (nv > 0) {                                  // wave-uniform branch
        float (*S)[17] = sh[wv];
        bool full = (nv >= 64);
        int nvc = full ? 64 : nv;
        bool active = lane < nv;
        const float* tw = tru + (size_t)cell0 * 85;

        int cidx = active ? (cell0 + lane) : (cells - 1);
        int hw = g * g;
        int ij = cidx % hw;
        int a  = (cidx / hw) % 3;
        int b  = cidx / (3 * hw);
        int i  = ij / g;
        int j  = ij - i * g;
        // raw[b][a][i][j][c] = y_pred[b][a*85+c][i][j] (channel stride hw, coalesced)
        const float* pb = pred + (size_t)((b * 3 + a) * 85) * hw + ij;

        // ---- stage head: ch 0..4 x 64 cells, flat f = cell*5+ch mapping ----
        {
            float hreg[5];
#pragma unroll
            for (int k = 0; k < 5; k++) {
                int f = k * 64 + lane;
                int cell = f / 5;
                int ch = f - cell * 5;
                int cc = full ? cell : min(cell, nvc - 1);
                hreg[k] = tw[cc * 85 + ch];
            }
#pragma unroll
            for (int k = 0; k < 5; k++) {
                int f = k * 64 + lane;
                int cell = f / 5;
                int ch = f - cell * 5;
                S[cell][ch] = hreg[k];
            }
        }

        float creg[16];
        stage_cls<0>(tw, lane, nvc, full, creg);   // chunk0 latency hides under head

        float cls = 0.f, mask = 0.f;
        if (active) {
            float y0 = S[lane][0], y1 = S[lane][1], y2 = S[lane][2], y3 = S[lane][3];
            mask = S[lane][4];

            float r0 = pb[0];
            float r1 = pb[hw];
            float r2 = pb[2 * hw];
            float r3 = pb[3 * hw];
            float r4 = pb[4 * hw];

            float gf = (float)g, gx = (float)j, gy = (float)i;
            float aw = c_anch[layer * 3 + a][0];
            float ah = c_anch[layer * 3 + a][1];

            // xy loss: bce(sigmoid(r), t) = softplus(r) - t*r
            float true_x = y0 * gf - gx;
            float true_y = y1 * gf - gy;
            float ls = 2.f - y2 * y3;   // loss_scale
            float lxy = (softplusf(r0) - true_x * r0) + (softplusf(r1) - true_y * r1);
            acc += mask * ls * lxy;

            // wh loss
            float tw_ = __logf(y2 * (416.f / aw));
            float th_ = __logf(y3 * (416.f / ah));
            float dw = r2 - tw_, dh = r3 - th_;
            acc += mask * ls * 0.5f * (dw * dw + dh * dh);

            // conf bce
            float cbce = softplusf(r4) - mask * r4;

            // IoU vs 20 targets -> neg mask
            float sx = sigmoidf(r0);
            float sy = sigmoidf(r1);
            float bx = __fdividef(sx + gx, gf);
            float by = __fdividef(sy + gy, gf);
            float bw = __expf(r2) * aw * (1.f / 416.f);
            float bh = __expf(r3) * ah * (1.f / 416.f);
            float a1 = bw * bh;
            float b1minx = bx - 0.5f * bw, b1maxx = bx + 0.5f * bw;
            float b1miny = by - 0.5f * bh, b1maxy = by + 0.5f * bh;

            const float* tg = tgt + b * 20 * 5;
            float best = 0.f;
#pragma unroll 5
            for (int k = 0; k < 20; k++) {
                f4a t = *reinterpret_cast<const f4a*>(tg + k * 5);  // tx,ty,tw,th
                float hw2 = 0.5f * t.z, hh2 = 0.5f * t.w;
                float iw = fminf(b1maxx, t.x + hw2) - fmaxf(b1minx, t.x - hw2);
                float ih = fminf(b1maxy, t.y + hh2) - fmaxf(b1miny, t.y - hh2);
                iw = fmaxf(iw, 0.f);
                ih = fmaxf(ih, 0.f);
                float inter = iw * ih;
                float iou = __fdividef(inter, a1 + t.z * t.w - inter);
                best = fmaxf(best, iou);
            }
            float neg = (best < 0.5f) ? 1.f : 0.f;
            acc += mask * cbce + (1.f - mask) * neg * cbce;
        }

        // ---- class chunks: write q / prefetch q+1 / consume q (wave-local) ----
        // write_cls(q) waits only on chunk-q loads (older than consume preds);
        // consume(q)'s own pred-load waits drain the queue, so the next
        // write_cls never adds a stall. ds_read->ds_write anti-dependence on S
        // is kept in order by the compiler (same array) and the in-order DS pipe.
        write_cls(S, lane, creg);
        stage_cls<1>(tw, lane, nvc, full, creg);
        if (active) cls += consume_cls<0>(S, pb, lane, hw);

        write_cls(S, lane, creg);
        stage_cls<2>(tw, lane, nvc, full, creg);
        if (active) cls += consume_cls<1>(S, pb, lane, hw);

        write_cls(S, lane, creg);
        stage_cls<3>(tw, lane, nvc, full, creg);
        if (active) cls += consume_cls<2>(S, pb, lane, hw);

        write_cls(S, lane, creg);
        stage_cls<4>(tw, lane, nvc, full, creg);
        if (active) cls += consume_cls<3>(S, pb, lane, hw);

        write_cls(S, lane, creg);
        if (active) {
            cls += consume_cls<4>(S, pb, lane, hw);
            acc += mask * cls;
        }
    }

    // ---- block reduction: wave shuffle then LDS (only barrier in the kernel) ----
    for (int off = 32; off > 0; off >>= 1)
        acc += __shfl_down(acc, off, 64);
    __shared__ float shr[BLOCK / 64];
    if ((threadIdx.x & 63) == 0)
        shr[threadIdx.x >> 6] = acc;
    __syncthreads();
    if (threadIdx.x == 0) {
        float s = 0.f;
        for (int w = 0; w < BLOCK / 64; w++) s += shr[w];
        partials[blockIdx.x] = s;
    }
}

__global__ __launch_bounds__(BLOCK) void yolo_loss_reduce(
    const float* __restrict__ partials, float* __restrict__ out)
{
    float s = 0.f;
    for (int i = threadIdx.x; i < NBLOCKS; i += BLOCK)
        s += partials[i];
    for (int off = 32; off > 0; off >>= 1)
        s += __shfl_down(s, off, 64);
    __shared__ float sh[BLOCK / 64];
    if ((threadIdx.x & 63) == 0)
        sh[threadIdx.x >> 6] = s;
    __syncthreads();
    if (threadIdx.x == 0) {
        float tot = 0.f;
        for (int wv = 0; wv < BLOCK / 64; wv++) tot += sh[wv];
        out[0] = tot;
    }
}

extern "C" void kernel_launch(void* const* d_in, const int* in_sizes, int n_in,
                              void* d_out, int out_size, void* d_ws, size_t ws_size,
                              hipStream_t stream) {
    // setup_inputs() dict order is INTERLEAVED:
    //   d_in[0]=y_pred0, d_in[1]=y_true0, d_in[2]=y_pred1, d_in[3]=y_true1,
    //   d_in[4]=y_pred2, d_in[5]=y_true2, d_in[6]=target
    const float* p0  = (const float*)d_in[0];
    const float* t0  = (const float*)d_in[1];
    const float* p1  = (const float*)d_in[2];
    const float* t1  = (const float*)d_in[3];
    const float* p2  = (const float*)d_in[4];
    const float* t2  = (const float*)d_in[5];
    const float* tgt = (const float*)d_in[6];
    float* partials  = (float*)d_ws;   // NBLOCKS floats; every slot written each call

    yolo_loss_main<<<NBLOCKS, BLOCK, 0, stream>>>(p0, p1, p2, t0, t1, t2, tgt, partials);
    yolo_loss_reduce<<<1, BLOCK, 0, stream>>>(partials, (float*)d_out);
}